// Round 10
// baseline (7620.459 us; speedup 1.0000x reference)
//
#include <hip/hip_runtime.h>
#include <hip/hip_bf16.h>
#include <math.h>

#define Tt 80
#define Vv 10000
#define Ee 100
#define Uu 512
#define ROWS 32
#define NBLK 128

typedef __attribute__((ext_vector_type(8))) short short8;
typedef __attribute__((ext_vector_type(4))) float f32x4;

__device__ __forceinline__ unsigned short f2bf(float f) {
    union { float f; unsigned u; } x{f};
    unsigned u = x.u;
    return (unsigned short)((u + 0x7fffu + ((u >> 16) & 1u)) >> 16);
}

// branch-free tanh via exp; clamp keeps e finite
__device__ __forceinline__ float tanh_fast(float x) {
    float z = fminf(fmaxf(x, -15.f), 15.f);
    float e = __expf(2.f * z);
    return (e - 1.f) / (e + 1.f);
}

// ---------------- P1: embW0 = emb@W0 + b0 (fp32, exact input term; 20MB, L3) ----------------
__global__ __launch_bounds__(512) void k_embw0(const float* __restrict__ emb,
                                               const float* __restrict__ W0,
                                               const float* __restrict__ b0,
                                               float* __restrict__ embW0) {
    __shared__ float semb[4][Ee];
    int v0 = blockIdx.x * 4;
    int tid = threadIdx.x;
    if (tid < 4 * Ee) semb[tid / Ee][tid % Ee] = emb[(v0 + tid / Ee) * Ee + tid % Ee];
    __syncthreads();
    float b = b0[tid];
    for (int vl = 0; vl < 4; ++vl) {
        float a = 0.f;
        #pragma unroll 4
        for (int e = 0; e < Ee; ++e) a += semb[vl][e] * W0[e * Uu + tid];
        embW0[(v0 + vl) * Uu + tid] = a + b;
    }
}

// ---------------- P2: pack U0, W1/U1 into 48 slice-major 32KB K-slices ----------------
// S<16: U0 ks=S.  S>=16: s2=S-16, ks=s2>>1, mat=(s2&1)?U1:W1.
// Within slice: [(ntg*64 + lane)*8 + j] = M[ks*32 + 8*(lane>>4) + j][ntg*16 + (lane&15)]
__global__ __launch_bounds__(256) void k_pack(const float* __restrict__ U0,
                                              const float* __restrict__ W1,
                                              const float* __restrict__ U1,
                                              unsigned short* __restrict__ pW) {
    int gid = blockIdx.x * 256 + threadIdx.x;   // 0 .. 98303 (48 * 32 * 64)
    int S = gid >> 11;
    int ntg = (gid >> 6) & 31;
    int lane = gid & 63;
    const float* src;
    int ks;
    if (S < 16) { src = U0; ks = S; }
    else { int s2 = S - 16; ks = s2 >> 1; src = (s2 & 1) ? U1 : W1; }
    int row0 = ks * 32 + (lane >> 4) * 8;
    int col = ntg * 16 + (lane & 15);
    short8 v;
    #pragma unroll
    for (int j = 0; j < 8; ++j) v[j] = (short)f2bf(src[(row0 + j) * Uu + col]);
    *(short8*)(pW + (size_t)gid * 8) = v;
}

// h-state hazard barrier: drain LDS ops, sync. NEVER waits vmcnt -> the per-wave
// register weight-stream pipeline stays in flight across it.
#define LG_SYNC() do { asm volatile("s_waitcnt lgkmcnt(0)" ::: "memory"); \
    __builtin_amdgcn_sched_barrier(0); __builtin_amdgcn_s_barrier(); \
    __builtin_amdgcn_sched_barrier(0); } while (0)

// load the 4 B-fragments of slice S for this wave into dst[0..3] (per-wave, no LDS)
#define BLOAD(S, dst)                                                          \
    {                                                                          \
        _Pragma("unroll")                                                      \
        for (int n_ = 0; n_ < 4; ++n_)                                         \
            dst[n_] = *(const short8*)(pWb +                                   \
                (((size_t)((S) * 32 + wv * 4 + n_) * 64 + lane) * 16));        \
    }

// one phase: issue next slice's loads, ds_read 2 A-frags from hb at K-slot KS,
// 8 MFMA with current fragments
#define PH(SNEXT, hb, KS, bcur, bnxt, acc)                                     \
    {                                                                          \
        BLOAD(SNEXT, bnxt);                                                    \
        short8 aA_ = *(const short8*)((hb) + (((ln) * 1024 + (KS) * 64 + q * 16) ^ swz));          \
        short8 aB_ = *(const short8*)((hb) + (((16 + ln) * 1024 + (KS) * 64 + q * 16) ^ swz));     \
        _Pragma("unroll")                                                      \
        for (int n_ = 0; n_ < 4; ++n_) {                                       \
            acc[0][n_] = __builtin_amdgcn_mfma_f32_16x16x32_bf16(aA_, bcur[n_], acc[0][n_], 0, 0, 0); \
            acc[1][n_] = __builtin_amdgcn_mfma_f32_16x16x32_bf16(aB_, bcur[n_], acc[1][n_], 0, 0, 0); \
        }                                                                      \
    }

__global__ __launch_bounds__(512) void k_rnn(const int* __restrict__ tokens,
                                             const float* __restrict__ embW0,
                                             const unsigned short* __restrict__ pWu,
                                             const float* __restrict__ b1,
                                             const float* __restrict__ Wout,
                                             const float* __restrict__ bout,
                                             float* __restrict__ out) {
    __shared__ __align__(16) char smem[65536];
    char* h0b = smem;                  // bf16 [32][512] swizzled, 32KB
    char* h1b = smem + 32768;          // bf16 [32][512] swizzled, 32KB
    float* finalb = (float*)smem;      // fp32 [32][512] overlay for epilogue (64KB)

    const int tid = threadIdx.x;
    const int lane = tid & 63;
    const int wv = tid >> 6;           // 0..7, owns cols wv*64 .. wv*64+63
    const int q = lane >> 4;
    const int ln = lane & 15;
    const int bbase = blockIdx.x * ROWS;
    const int swz = (ln & 7) << 4;
    const char* pWb = (const char*)pWu;

    // zero h buffers (64KB)
    {
        uint4 z = {0u, 0u, 0u, 0u};
        #pragma unroll
        for (int i = 0; i < 8; ++i) ((uint4*)smem)[tid + i * 512] = z;
    }
    __syncthreads();

    float b1c[4];
    #pragma unroll
    for (int n = 0; n < 4; ++n) b1c[n] = b1[wv * 64 + n * 16 + ln];
    float wout8[8];
    #pragma unroll
    for (int j = 0; j < 8; ++j) wout8[j] = Wout[lane * 8 + j];
    float boutv = bout[0];

    // register ping-pong for the weight stream
    short8 bA[4], bB[4];
    BLOAD(0, bA);   // prologue: slice 0

    // gather for t=0 (exact fp32 input term): gx[m][n][r]
    float gx[2][4][4];
    #pragma unroll
    for (int m = 0; m < 2; ++m)
        #pragma unroll
        for (int r = 0; r < 4; ++r) {
            int tk = tokens[(bbase + m * 16 + q * 4 + r) * Tt + 0];
            #pragma unroll
            for (int n = 0; n < 4; ++n)
                gx[m][n][r] = __builtin_nontemporal_load(
                    &embW0[(size_t)tk * Uu + wv * 64 + n * 16 + ln]);
        }

    for (int t = 0; t < Tt; ++t) {
        // ---------- layer 0: acc0 = gather + h0_old @ U0 (slices 0..15) ----------
        f32x4 acc0[2][4];
        #pragma unroll
        for (int m = 0; m < 2; ++m)
            #pragma unroll
            for (int n = 0; n < 4; ++n)
                #pragma unroll
                for (int r = 0; r < 4; ++r) acc0[m][n][r] = gx[m][n][r];

        #pragma unroll
        for (int S2 = 0; S2 < 8; ++S2) {
            PH(2 * S2 + 1, h0b, 2 * S2,     bA, bB, acc0);
            PH(2 * S2 + 2, h0b, 2 * S2 + 1, bB, bA, acc0);
        }
        // (phase 15 loaded slice 16 into bA)

        f32x4 th0[2][4];
        #pragma unroll
        for (int m = 0; m < 2; ++m)
            #pragma unroll
            for (int n = 0; n < 4; ++n)
                #pragma unroll
                for (int r = 0; r < 4; ++r) th0[m][n][r] = tanh_fast(acc0[m][n][r]);

        LG_SYNC();   // BAR_A: all waves done reading h0_old (and h1 write of t-1 drained)
        #pragma unroll
        for (int m = 0; m < 2; ++m)
            #pragma unroll
            for (int n = 0; n < 4; ++n)
                #pragma unroll
                for (int r = 0; r < 4; ++r) {
                    int row = m * 16 + q * 4 + r;
                    int col = wv * 64 + n * 16 + ln;
                    *(unsigned short*)(h0b + ((row * 1024 + col * 2) ^ ((row & 7) << 4)))
                        = f2bf(th0[m][n][r]);
                }
        LG_SYNC();   // BAR_B: h0_new published

        // prefetch next step's gather (consumed at t+1 top; ~32 phases of cover)
        if (t + 1 < Tt) {
            #pragma unroll
            for (int m = 0; m < 2; ++m)
                #pragma unroll
                for (int r = 0; r < 4; ++r) {
                    int tk = tokens[(bbase + m * 16 + q * 4 + r) * Tt + t + 1];
                    #pragma unroll
                    for (int n = 0; n < 4; ++n)
                        gx[m][n][r] = __builtin_nontemporal_load(
                            &embW0[(size_t)tk * Uu + wv * 64 + n * 16 + ln]);
                }
        }

        // ---------- layer 1: acc1 = b1 + h0_new @ W1 + h1_old @ U1 (slices 16..47) ----------
        f32x4 acc1[2][4];
        #pragma unroll
        for (int m = 0; m < 2; ++m)
            #pragma unroll
            for (int n = 0; n < 4; ++n)
                #pragma unroll
                for (int r = 0; r < 4; ++r) acc1[m][n][r] = b1c[n];

        #pragma unroll
        for (int k2 = 0; k2 < 16; ++k2) {
            PH(17 + 2 * k2, h0b, k2, bA, bB, acc1);                 // W1 phase (even S)
            PH((18 + 2 * k2) % 48, h1b, k2, bB, bA, acc1);          // U1 phase (odd S)
        }
        // (phase 47 loaded slice 0 into bA for next step)

        f32x4 th1[2][4];
        #pragma unroll
        for (int m = 0; m < 2; ++m)
            #pragma unroll
            for (int n = 0; n < 4; ++n)
                #pragma unroll
                for (int r = 0; r < 4; ++r) th1[m][n][r] = tanh_fast(acc1[m][n][r]);

        LG_SYNC();   // BAR_C: all waves done reading h1_old (and h0_new)
        if (t < Tt - 1) {
            #pragma unroll
            for (int m = 0; m < 2; ++m)
                #pragma unroll
                for (int n = 0; n < 4; ++n)
                    #pragma unroll
                    for (int r = 0; r < 4; ++r) {
                        int row = m * 16 + q * 4 + r;
                        int col = wv * 64 + n * 16 + ln;
                        *(unsigned short*)(h1b + ((row * 1024 + col * 2) ^ ((row & 7) << 4)))
                            = f2bf(th1[m][n][r]);
                    }
            // publish happens at next step's BAR_A (lgkmcnt(0) there drains these writes)
        } else {
            #pragma unroll
            for (int m = 0; m < 2; ++m)
                #pragma unroll
                for (int n = 0; n < 4; ++n)
                    #pragma unroll
                    for (int r = 0; r < 4; ++r)
                        finalb[(m * 16 + q * 4 + r) * Uu + wv * 64 + n * 16 + ln] = th1[m][n][r];
        }
    }

    LG_SYNC();   // finalb visible

    // out[row] = sigmoid(h1[row,:] @ Wout + bout); wave wv -> rows wv*4 .. wv*4+3
    #pragma unroll
    for (int rr = 0; rr < 4; ++rr) {
        int row = wv * 4 + rr;
        float s = 0.f;
        #pragma unroll
        for (int j = 0; j < 8; ++j)
            s += finalb[row * Uu + lane * 8 + j] * wout8[j];
        #pragma unroll
        for (int off = 32; off; off >>= 1) s += __shfl_xor(s, off);
        if (lane == 0) out[bbase + row] = 1.f / (1.f + __expf(-(s + boutv)));
    }
}

extern "C" void kernel_launch(void* const* d_in, const int* in_sizes, int n_in,
                              void* d_out, int out_size, void* d_ws, size_t ws_size,
                              hipStream_t stream) {
    const int*   tokens = (const int*)d_in[0];
    const float* emb    = (const float*)d_in[1];
    const float* W0     = (const float*)d_in[2];
    const float* U0     = (const float*)d_in[3];
    const float* b0     = (const float*)d_in[4];
    const float* W1     = (const float*)d_in[5];
    const float* U1     = (const float*)d_in[6];
    const float* b1     = (const float*)d_in[7];
    const float* Wout   = (const float*)d_in[8];
    const float* bout   = (const float*)d_in[9];
    float* outp = (float*)d_out;

    char* ws = (char*)d_ws;
    float* embW0 = (float*)ws;                                   // 20,480,000 B
    unsigned short* pW = (unsigned short*)(ws + 20480000);       // 48*32KB = 1,572,864 B

    hipLaunchKernelGGL(k_embw0, dim3(Vv / 4), dim3(512), 0, stream, emb, W0, b0, embW0);
    hipLaunchKernelGGL(k_pack, dim3(384), dim3(256), 0, stream, U0, W1, U1, pW);
    hipLaunchKernelGGL(k_rnn, dim3(NBLK), dim3(512), 0, stream,
                       tokens, embW0, pW, b1, Wout, bout, outp);
}

// Round 11
// 2626.350 us; speedup vs baseline: 2.9015x; 2.9015x over previous
//
#include <hip/hip_runtime.h>
#include <hip/hip_bf16.h>
#include <math.h>

#define Tt 80
#define Vv 10000
#define Ee 100
#define Uu 512
#define ROWS 32
#define NBLK 128
#define SLICE_B 32768

typedef __attribute__((ext_vector_type(8))) short short8;
typedef __attribute__((ext_vector_type(4))) float f32x4;
typedef __attribute__((ext_vector_type(4))) unsigned u32x4;

__device__ __forceinline__ unsigned short f2bf(float f) {
    union { float f; unsigned u; } x{f};
    unsigned u = x.u;
    return (unsigned short)((u + 0x7fffu + ((u >> 16) & 1u)) >> 16);
}

__device__ __forceinline__ short8 as_s8(u32x4 v) {
    union { u32x4 u; short8 s; } p;
    p.u = v;
    return p.s;
}

// branch-free tanh via exp; clamp keeps e finite
__device__ __forceinline__ float tanh_fast(float x) {
    float z = fminf(fmaxf(x, -15.f), 15.f);
    float e = __expf(2.f * z);
    return (e - 1.f) / (e + 1.f);
}

// ---------------- P1: embW0 = emb@W0 + b0 (fp32, exact input term; 20MB, L3) ----------------
__global__ __launch_bounds__(512) void k_embw0(const float* __restrict__ emb,
                                               const float* __restrict__ W0,
                                               const float* __restrict__ b0,
                                               float* __restrict__ embW0) {
    __shared__ float semb[4][Ee];
    int v0 = blockIdx.x * 4;
    int tid = threadIdx.x;
    if (tid < 4 * Ee) semb[tid / Ee][tid % Ee] = emb[(v0 + tid / Ee) * Ee + tid % Ee];
    __syncthreads();
    float b = b0[tid];
    for (int vl = 0; vl < 4; ++vl) {
        float a = 0.f;
        #pragma unroll 4
        for (int e = 0; e < Ee; ++e) a += semb[vl][e] * W0[e * Uu + tid];
        embW0[(v0 + vl) * Uu + tid] = a + b;
    }
}

// ---------------- P2: pack U0, W1/U1 into 48 slice-major 32KB K-slices ----------------
// S<16: U0 ks=S.  S>=16: s2=S-16, ks=s2>>1, mat=(s2&1)?U1:W1.
// Within slice: [(ntg*64 + lane)*8 + j] = M[ks*32 + 8*(lane>>4) + j][ntg*16 + (lane&15)]
__global__ __launch_bounds__(256) void k_pack(const float* __restrict__ U0,
                                              const float* __restrict__ W1,
                                              const float* __restrict__ U1,
                                              unsigned short* __restrict__ pW) {
    int gid = blockIdx.x * 256 + threadIdx.x;   // 0 .. 98303 (48 * 32 * 64)
    int S = gid >> 11;
    int ntg = (gid >> 6) & 31;
    int lane = gid & 63;
    const float* src;
    int ks;
    if (S < 16) { src = U0; ks = S; }
    else { int s2 = S - 16; ks = s2 >> 1; src = (s2 & 1) ? U1 : W1; }
    int row0 = ks * 32 + (lane >> 4) * 8;
    int col = ntg * 16 + (lane & 15);
    short8 v;
    #pragma unroll
    for (int j = 0; j < 8; ++j) v[j] = (short)f2bf(src[(row0 + j) * Uu + col]);
    *(short8*)(pW + (size_t)gid * 8) = v;
}

// counted vmcnt wait + scheduler fence (rule #18)
#define VMW(N) do { asm volatile("s_waitcnt vmcnt(" #N ")" ::: "memory"); \
    __builtin_amdgcn_sched_barrier(0); } while (0)

// h-hazard barrier: drains LDS only; vmcnt queue (weight pipeline) stays in flight
#define LG_SYNC() do { asm volatile("s_waitcnt lgkmcnt(0)" ::: "memory"); \
    __builtin_amdgcn_sched_barrier(0); __builtin_amdgcn_s_barrier(); \
    __builtin_amdgcn_sched_barrier(0); } while (0)

// issue this wave's 2 B-fragments of slice S into register ring slot (asm: opaque to
// the compiler's waitcnt pass -> our counted VMW()s are the only ordering)
#define BISSUE(S, slot) do { \
    const char* wa_ = pWb + wvoff + (size_t)(S) * SLICE_B; \
    asm volatile("global_load_dwordx4 %0, %2, off\n\t" \
                 "global_load_dwordx4 %1, %2, off offset:1024" \
                 : "=&v"(bf[slot][0]), "=&v"(bf[slot][1]) \
                 : "v"(wa_)); \
} while (0)

// issue the 16 gather dwords for step T (counted: 16 vmem instructions)
#define GISSUE(T) do { \
    _Pragma("unroll") \
    for (int m_ = 0; m_ < 2; ++m_) { \
        _Pragma("unroll") \
        for (int r_ = 0; r_ < 4; ++r_) { \
            int tk_ = stok[(m_ * 16 + q * 4 + r_) * Tt + (T)]; \
            const float* ga_ = embW0 + (size_t)tk_ * Uu + wv * 32 + ln; \
            asm volatile("global_load_dword %0, %2, off\n\t" \
                         "global_load_dword %1, %2, off offset:64" \
                         : "=&v"(gx[m_][0][r_]), "=&v"(gx[m_][1][r_]) \
                         : "v"(ga_)); \
        } \
    } \
} while (0)

__global__ __launch_bounds__(1024, 4)
void k_rnn(const int* __restrict__ tokens,
           const float* __restrict__ embW0,
           const unsigned short* __restrict__ pWu,
           const float* __restrict__ b1,
           const float* __restrict__ Wout,
           const float* __restrict__ bout,
           float* __restrict__ out) {
    __shared__ __align__(16) char smem[65536 + ROWS * Tt * 4];
    char* h0b = smem;                    // bf16 [32][512] swizzled, 32KB
    char* h1b = smem + 32768;            // bf16 [32][512] swizzled, 32KB
    int* stok = (int*)(smem + 65536);    // [32][80] tokens
    float* finalb = (float*)smem;        // fp32 [32][512] overlay for epilogue

    const int tid = threadIdx.x;
    const int lane = tid & 63;
    const int wv = tid >> 6;             // 0..15, owns cols wv*32 .. wv*32+31
    const int q = lane >> 4;
    const int ln = lane & 15;
    const int bbase = blockIdx.x * ROWS;
    const int swz = (ln & 7) << 4;
    const char* pWb = (const char*)pWu;
    const int wvoff = wv * 2048 + lane * 16;   // byte offset of ntg=wv*2, this lane

    // zero h buffers (64KB)
    {
        uint4 z = {0u, 0u, 0u, 0u};
        #pragma unroll
        for (int i = 0; i < 4; ++i) ((uint4*)smem)[tid + i * 1024] = z;
    }
    // stage token slab
    for (int i = tid; i < ROWS * Tt; i += 1024) stok[i] = tokens[bbase * Tt + i];

    float b1c[2];
    #pragma unroll
    for (int n = 0; n < 2; ++n) b1c[n] = b1[wv * 32 + n * 16 + ln];
    float wout8[8];
    #pragma unroll
    for (int j = 0; j < 8; ++j) wout8[j] = Wout[lane * 8 + j];
    float boutv = bout[0];

    __syncthreads();   // full drain: vmcnt queue empty, LDS (h zeros, stok) visible

    u32x4 bf[3][2];        // 3-slot register ring, 2 fragments each
    float gx[2][2][4];     // input-term gather

    // prime: gathers for t=0 (16 loads), then slices 0,1 (2+2 loads)
    GISSUE(0);
    BISSUE(0, 0);
    BISSUE(1, 1);

    for (int t = 0; t < Tt; ++t) {
        VMW(4);   // gathers done (t=0: drains G; t>0: no-op, queue=[A0,A1])
        f32x4 acc0[2][2];
        #pragma unroll
        for (int m = 0; m < 2; ++m)
            #pragma unroll
            for (int n = 0; n < 2; ++n)
                #pragma unroll
                for (int r = 0; r < 4; ++r) acc0[m][n][r] = gx[m][n][r];

        // ---------- layer 0: phases p=0..15 (U0), no barriers ----------
        #pragma unroll
        for (int p = 0; p < 16; ++p) {
            VMW(2);   // slice p landed (issued 2 phases ago)
            BISSUE((p + 2) % 48, (p + 2) % 3);
            short8 aA = *(const short8*)(h0b + ((ln * 1024 + p * 64 + q * 16) ^ swz));
            short8 aB = *(const short8*)(h0b + (((16 + ln) * 1024 + p * 64 + q * 16) ^ swz));
            #pragma unroll
            for (int n = 0; n < 2; ++n) {
                acc0[0][n] = __builtin_amdgcn_mfma_f32_16x16x32_bf16(aA, as_s8(bf[p % 3][n]), acc0[0][n], 0, 0, 0);
                acc0[1][n] = __builtin_amdgcn_mfma_f32_16x16x32_bf16(aB, as_s8(bf[p % 3][n]), acc0[1][n], 0, 0, 0);
            }
        }

        float th0[2][2][4];
        #pragma unroll
        for (int m = 0; m < 2; ++m)
            #pragma unroll
            for (int n = 0; n < 2; ++n)
                #pragma unroll
                for (int r = 0; r < 4; ++r) th0[m][n][r] = tanh_fast(acc0[m][n][r]);

        LG_SYNC();   // BAR_A: all waves done reading h0_old (h1 writes of t-1 drained)
        #pragma unroll
        for (int m = 0; m < 2; ++m)
            #pragma unroll
            for (int n = 0; n < 2; ++n)
                #pragma unroll
                for (int r = 0; r < 4; ++r) {
                    int row = m * 16 + q * 4 + r;
                    int col = wv * 32 + n * 16 + ln;
                    *(unsigned short*)(h0b + ((row * 1024 + col * 2) ^ ((row & 7) << 4)))
                        = f2bf(th0[m][n][r]);
                }
        LG_SYNC();   // BAR_B: h0_new published

        // issue next step's gathers (uniform count; t=79 data unused)
        GISSUE(t + 1 < Tt ? t + 1 : 0);

        // ---------- layer 1: phases p=16..47 (W1/U1 interleaved), no barriers ----------
        f32x4 acc1[2][2];
        #pragma unroll
        for (int m = 0; m < 2; ++m)
            #pragma unroll
            for (int n = 0; n < 2; ++n)
                #pragma unroll
                for (int r = 0; r < 4; ++r) acc1[m][n][r] = b1c[n];

        #pragma unroll
        for (int p = 16; p < 48; ++p) {
            if (p < 18) { VMW(18); }   // gathers (16) still behind slices 16/17 in FIFO
            else        { VMW(2);  }
            BISSUE((p + 2) % 48, (p + 2) % 3);
            const int k2 = (p - 16) >> 1;
            const char* hsrc = ((p - 16) & 1) ? h1b : h0b;   // even: W1 x h0_new, odd: U1 x h1_old
            short8 aA = *(const short8*)(hsrc + ((ln * 1024 + k2 * 64 + q * 16) ^ swz));
            short8 aB = *(const short8*)(hsrc + (((16 + ln) * 1024 + k2 * 64 + q * 16) ^ swz));
            #pragma unroll
            for (int n = 0; n < 2; ++n) {
                acc1[0][n] = __builtin_amdgcn_mfma_f32_16x16x32_bf16(aA, as_s8(bf[p % 3][n]), acc1[0][n], 0, 0, 0);
                acc1[1][n] = __builtin_amdgcn_mfma_f32_16x16x32_bf16(aB, as_s8(bf[p % 3][n]), acc1[1][n], 0, 0, 0);
            }
        }

        float th1[2][2][4];
        #pragma unroll
        for (int m = 0; m < 2; ++m)
            #pragma unroll
            for (int n = 0; n < 2; ++n)
                #pragma unroll
                for (int r = 0; r < 4; ++r) th1[m][n][r] = tanh_fast(acc1[m][n][r]);

        LG_SYNC();   // BAR_C: all waves done reading h1_old (and h0_new)
        if (t < Tt - 1) {
            #pragma unroll
            for (int m = 0; m < 2; ++m)
                #pragma unroll
                for (int n = 0; n < 2; ++n)
                    #pragma unroll
                    for (int r = 0; r < 4; ++r) {
                        int row = m * 16 + q * 4 + r;
                        int col = wv * 32 + n * 16 + ln;
                        *(unsigned short*)(h1b + ((row * 1024 + col * 2) ^ ((row & 7) << 4)))
                            = f2bf(th1[m][n][r]);
                    }
            // published by next step's BAR_A
        } else {
            #pragma unroll
            for (int m = 0; m < 2; ++m)
                #pragma unroll
                for (int n = 0; n < 2; ++n)
                    #pragma unroll
                    for (int r = 0; r < 4; ++r)
                        finalb[(m * 16 + q * 4 + r) * Uu + wv * 32 + n * 16 + ln] = th1[m][n][r];
        }
    }

    // ---------------- epilogue ----------------
    asm volatile("s_waitcnt vmcnt(0) lgkmcnt(0)" ::: "memory");
    __builtin_amdgcn_sched_barrier(0);
    __builtin_amdgcn_s_barrier();
    __builtin_amdgcn_sched_barrier(0);

    // out[row] = sigmoid(h1[row,:] @ Wout + bout); wave wv -> rows 2wv, 2wv+1
    #pragma unroll
    for (int rr = 0; rr < 2; ++rr) {
        int row = wv * 2 + rr;
        float s = 0.f;
        #pragma unroll
        for (int j = 0; j < 8; ++j)
            s += finalb[row * Uu + lane * 8 + j] * wout8[j];
        #pragma unroll
        for (int off = 32; off; off >>= 1) s += __shfl_xor(s, off);
        if (lane == 0) out[bbase + row] = 1.f / (1.f + __expf(-(s + boutv)));
    }
}

extern "C" void kernel_launch(void* const* d_in, const int* in_sizes, int n_in,
                              void* d_out, int out_size, void* d_ws, size_t ws_size,
                              hipStream_t stream) {
    const int*   tokens = (const int*)d_in[0];
    const float* emb    = (const float*)d_in[1];
    const float* W0     = (const float*)d_in[2];
    const float* U0     = (const float*)d_in[3];
    const float* b0     = (const float*)d_in[4];
    const float* W1     = (const float*)d_in[5];
    const float* U1     = (const float*)d_in[6];
    const float* b1     = (const float*)d_in[7];
    const float* Wout   = (const float*)d_in[8];
    const float* bout   = (const float*)d_in[9];
    float* outp = (float*)d_out;

    char* ws = (char*)d_ws;
    float* embW0 = (float*)ws;                                   // 20,480,000 B
    unsigned short* pW = (unsigned short*)(ws + 20480000);       // 48*32KB = 1,572,864 B

    hipLaunchKernelGGL(k_embw0, dim3(Vv / 4), dim3(512), 0, stream, emb, W0, b0, embW0);
    hipLaunchKernelGGL(k_pack, dim3(384), dim3(256), 0, stream, U0, W1, U1, pW);
    hipLaunchKernelGGL(k_rnn, dim3(NBLK), dim3(1024), 0, stream,
                       tokens, embW0, pW, b1, Wout, bout, outp);
}

// Round 13
// 886.098 us; speedup vs baseline: 8.6000x; 2.9639x over previous
//
#include <hip/hip_runtime.h>
#include <hip/hip_bf16.h>
#include <math.h>

#define Tt 80
#define Vv 10000
#define Ee 100
#define Uu 512
#define ROWS 16
#define NBLK 256
#define SLICE_B 32768
#define NSLICE 24   // 8 U0 + 8x(W1,U1) interleaved, K=64 per slice (int8)

typedef __attribute__((ext_vector_type(4))) int i32x4;
typedef __attribute__((ext_vector_type(4))) unsigned u32x4;

__device__ __forceinline__ i32x4 as_i4(u32x4 v) {
    union { u32x4 u; i32x4 i; } p;
    p.u = v;
    return p.i;
}

// branch-free tanh via exp; clamp keeps e finite
__device__ __forceinline__ float tanh_fast(float x) {
    float z = fminf(fmaxf(x, -15.f), 15.f);
    float e = __expf(2.f * z);
    return (e - 1.f) / (e + 1.f);
}

// ---------------- P1: embW0 = emb@W0 + b0 (fp32, exact input term; 20MB, L3) ----------------
__global__ __launch_bounds__(512) void k_embw0(const float* __restrict__ emb,
                                               const float* __restrict__ W0,
                                               const float* __restrict__ b0,
                                               float* __restrict__ embW0) {
    __shared__ float semb[4][Ee];
    int v0 = blockIdx.x * 4;
    int tid = threadIdx.x;
    if (tid < 4 * Ee) semb[tid / Ee][tid % Ee] = emb[(v0 + tid / Ee) * Ee + tid % Ee];
    __syncthreads();
    float b = b0[tid];
    for (int vl = 0; vl < 4; ++vl) {
        float a = 0.f;
        #pragma unroll 4
        for (int e = 0; e < Ee; ++e) a += semb[vl][e] * W0[e * Uu + tid];
        embW0[(v0 + vl) * Uu + tid] = a + b;
    }
}

// ---------------- P2a: per-column absmax for U0, W1, U1 -> scl[1536] ----------------
__global__ __launch_bounds__(256) void k_scale(const float* __restrict__ U0,
                                               const float* __restrict__ W1,
                                               const float* __restrict__ U1,
                                               float* __restrict__ scl) {
    int w = blockIdx.x * 4 + (threadIdx.x >> 6);   // wave id = column slot, 0..1535
    int lane = threadIdx.x & 63;
    int mat = w >> 9, col = w & 511;
    const float* src = (mat == 0) ? U0 : (mat == 1) ? W1 : U1;
    float v = 0.f;
    #pragma unroll
    for (int i = 0; i < 8; ++i) v = fmaxf(v, fabsf(src[(lane + i * 64) * Uu + col]));
    #pragma unroll
    for (int o = 32; o; o >>= 1) v = fmaxf(v, __shfl_xor(v, o));
    if (lane == 0) scl[w] = v;
}

// ---------------- P2b: pack into 24 slice-major 32KB int8 K64-slices, per-col scale ----------------
// S<8: U0 slot S (scale scl[col]). S>=8: s2=S-8, slot=s2>>1, mat=(s2&1)?U1:W1
// (combined scale max(scl[512+col], scl[1024+col])).
// byte addr: ((S*32 + ntg)*64 + lane)*16 + j ; k = slot*64 + (lane>>4)*16 + j ; col = ntg*16 + (lane&15)
__global__ __launch_bounds__(256) void k_pack(const float* __restrict__ U0,
                                              const float* __restrict__ W1,
                                              const float* __restrict__ U1,
                                              const float* __restrict__ scl,
                                              char* __restrict__ pW) {
    int gid = blockIdx.x * 256 + threadIdx.x;   // 0 .. 49151 (24 * 32 * 64)
    int S = gid >> 11;
    int ntg = (gid >> 6) & 31;
    int lane = gid & 63;
    int col = ntg * 16 + (lane & 15);
    const float* src;
    int slot;
    float a;
    if (S < 8) { src = U0; slot = S; a = scl[col]; }
    else {
        int s2 = S - 8;
        slot = s2 >> 1;
        src = (s2 & 1) ? U1 : W1;
        a = fmaxf(scl[512 + col], scl[1024 + col]);
    }
    float inv = 127.0f / a;
    int k0 = slot * 64 + (lane >> 4) * 16;
    union { char c[16]; uint4 u; } v;
    #pragma unroll
    for (int j = 0; j < 16; ++j) {
        int q = (int)rintf(src[(k0 + j) * Uu + col] * inv);
        q = q > 127 ? 127 : (q < -127 ? -127 : q);
        v.c[j] = (char)q;
    }
    *(uint4*)(pW + (size_t)gid * 16) = v.u;
}

// counted vmcnt wait + scheduler fence (rule #18)
#define VMW(N) do { asm volatile("s_waitcnt vmcnt(" #N ")" ::: "memory"); \
    __builtin_amdgcn_sched_barrier(0); } while (0)

// h-hazard barrier: drains LDS only; vmcnt queue (weight pipeline) stays in flight
#define LG_SYNC() do { asm volatile("s_waitcnt lgkmcnt(0)" ::: "memory"); \
    __builtin_amdgcn_sched_barrier(0); __builtin_amdgcn_s_barrier(); \
    __builtin_amdgcn_sched_barrier(0); } while (0)

// issue this wave's 2 B-fragments of slice S into register ring slot
#define BISSUE(S, slot) do { \
    const char* wa_ = pWb + wvoff + (size_t)(S) * SLICE_B; \
    asm volatile("global_load_dwordx4 %0, %2, off\n\t" \
                 "global_load_dwordx4 %1, %2, off offset:1024" \
                 : "=&v"(bf[slot][0]), "=&v"(bf[slot][1]) \
                 : "v"(wa_)); \
} while (0)

// issue the 8 gather dwords for step T (8 vmem instructions, counted)
#define GISSUE(T) do { \
    _Pragma("unroll") \
    for (int r_ = 0; r_ < 4; ++r_) { \
        int tk_ = stok[(q * 4 + r_) * Tt + (T)]; \
        const float* ga_ = embW0 + (size_t)tk_ * Uu + wv * 32 + ln; \
        asm volatile("global_load_dword %0, %2, off\n\t" \
                     "global_load_dword %1, %2, off offset:64" \
                     : "=&v"(gx[0][r_]), "=&v"(gx[1][r_]) \
                     : "v"(ga_)); \
    } \
} while (0)

__global__ __launch_bounds__(1024, 4)
void k_rnn(const int* __restrict__ tokens,
           const float* __restrict__ embW0,
           const char* __restrict__ pWu,
           const float* __restrict__ scl,
           const float* __restrict__ b1,
           const float* __restrict__ Wout,
           const float* __restrict__ bout,
           float* __restrict__ out) {
    __shared__ __align__(16) char smem[32768 + ROWS * Tt * 4];
    char* h0c = smem;                    // int8 coarse [16][512] swizzled, 8KB
    char* h0f = smem + 8192;             // int8 fine
    char* h1c = smem + 16384;
    char* h1f = smem + 24576;
    int* stok = (int*)(smem + 32768);    // [16][80] tokens
    float* finalb = (float*)smem;        // fp32 [16][512] overlay for epilogue (32KB)

    const int tid = threadIdx.x;
    const int lane = tid & 63;
    const int wv = tid >> 6;             // 0..15, owns cols wv*32 .. wv*32+31
    const int q = lane >> 4;
    const int ln = lane & 15;
    const int bbase = blockIdx.x * ROWS;
    const int swz = (ln & 7) << 4;
    const char* pWb = pWu;
    const int wvoff = wv * 2048 + lane * 16;   // byte offset of ntg=wv*2, this lane
    const float r127 = 1.0f / 127.0f;

    // zero h buffers (32KB)
    {
        uint4 z = {0u, 0u, 0u, 0u};
        #pragma unroll
        for (int i = 0; i < 2; ++i) ((uint4*)smem)[tid + i * 1024] = z;
    }
    // stage token slab
    for (int i = tid; i < ROWS * Tt; i += 1024) stok[i] = tokens[bbase * Tt + i];

    // per-column dequant constants: DQ = col_absmax / 127^2
    float DQ0[2], DQ1[2], b1c[2];
    #pragma unroll
    for (int n = 0; n < 2; ++n) {
        int col = wv * 32 + n * 16 + ln;
        DQ0[n] = scl[col] / 16129.0f;
        DQ1[n] = fmaxf(scl[512 + col], scl[1024 + col]) / 16129.0f;
        b1c[n] = b1[col];
    }
    float wout8[8];
    #pragma unroll
    for (int j = 0; j < 8; ++j) wout8[j] = Wout[lane * 8 + j];
    float boutv = bout[0];

    __syncthreads();   // vmcnt queue empty, LDS (h zeros, stok) visible

    u32x4 bf[3][2];    // 3-slot register ring, 2 fragments each
    float gx[2][4];    // input-term gather (fp32, incl. b0)

    // prime: gathers for t=0 (8 loads), slices 0,1 (4 loads); drain G, keep S0,S1
    GISSUE(0);
    BISSUE(0, 0);
    BISSUE(1, 1);
    VMW(4);

    for (int t = 0; t < Tt; ++t) {
        // ---------- layer 0: phases p=0..7 (U0), dual-h, no barriers ----------
        i32x4 accC[2], accF[2];
        #pragma unroll
        for (int n = 0; n < 2; ++n)
            #pragma unroll
            for (int r = 0; r < 4; ++r) { accC[n][r] = 0; accF[n][r] = 0; }

        #pragma unroll
        for (int p = 0; p < 8; ++p) {
            VMW(2);   // slice p landed (issued 2 phases ago)
            BISSUE(p + 2, (p + 2) % 3);
            int off = (ln * 512 + p * 64 + q * 16) ^ swz;
            i32x4 aC = *(const i32x4*)(h0c + off);
            i32x4 aF = *(const i32x4*)(h0f + off);
            #pragma unroll
            for (int n = 0; n < 2; ++n) {
                accC[n] = __builtin_amdgcn_mfma_i32_16x16x64_i8(aC, as_i4(bf[p % 3][n]), accC[n], 0, 0, 0);
                accF[n] = __builtin_amdgcn_mfma_i32_16x16x64_i8(aF, as_i4(bf[p % 3][n]), accF[n], 0, 0, 0);
            }
        }

        // dequant (per-col scale) + exact fp32 input term + tanh
        float th0[2][4];
        #pragma unroll
        for (int n = 0; n < 2; ++n)
            #pragma unroll
            for (int r = 0; r < 4; ++r)
                th0[n][r] = tanh_fast(gx[n][r] + DQ0[n] * ((float)accC[n][r] + (float)accF[n][r] * r127));

        LG_SYNC();   // BAR_A: all waves done reading h0_old (h1 writes of t-1 drained)
        #pragma unroll
        for (int n = 0; n < 2; ++n)
            #pragma unroll
            for (int r = 0; r < 4; ++r) {
                int row = q * 4 + r;
                int col = wv * 32 + n * 16 + ln;
                int off = (row * 512 + col) ^ ((row & 7) << 4);
                float t127 = th0[n][r] * 127.f;
                float hc = rintf(t127);
                h0c[off] = (char)(int)hc;
                h0f[off] = (char)(int)rintf((t127 - hc) * 127.f);
            }
        LG_SYNC();   // BAR_B: h0_new published

        // issue next step's gathers (uniform count; t=79 data unused)
        GISSUE(t + 1 < Tt ? t + 1 : 0);

        // ---------- layer 1: phases p=8..23 (W1/U1 interleaved, combined scale) ----------
        i32x4 a1C[2], a1F[2];
        #pragma unroll
        for (int n = 0; n < 2; ++n)
            #pragma unroll
            for (int r = 0; r < 4; ++r) { a1C[n][r] = 0; a1F[n][r] = 0; }

        #pragma unroll
        for (int p = 8; p < 24; ++p) {
            if (p < 10) { VMW(10); }   // gathers (8) sit behind slices 8/9 in the FIFO
            else        { VMW(2);  }
            BISSUE((p + 2) % NSLICE, (p + 2) % 3);
            const int idx = p - 8;
            const int k2 = idx >> 1;
            const char* hc_ = (idx & 1) ? h1c : h0c;   // even: W1 x h0_new, odd: U1 x h1_old
            const char* hf_ = (idx & 1) ? h1f : h0f;
            int off = (ln * 512 + k2 * 64 + q * 16) ^ swz;
            i32x4 aC = *(const i32x4*)(hc_ + off);
            i32x4 aF = *(const i32x4*)(hf_ + off);
            #pragma unroll
            for (int n = 0; n < 2; ++n) {
                a1C[n] = __builtin_amdgcn_mfma_i32_16x16x64_i8(aC, as_i4(bf[p % 3][n]), a1C[n], 0, 0, 0);
                a1F[n] = __builtin_amdgcn_mfma_i32_16x16x64_i8(aF, as_i4(bf[p % 3][n]), a1F[n], 0, 0, 0);
            }
        }

        float th1[2][4];
        #pragma unroll
        for (int n = 0; n < 2; ++n)
            #pragma unroll
            for (int r = 0; r < 4; ++r)
                th1[n][r] = tanh_fast(b1c[n] + DQ1[n] * ((float)a1C[n][r] + (float)a1F[n][r] * r127));

        LG_SYNC();   // BAR_C: all waves done reading h1_old (and h0_new)
        if (t < Tt - 1) {
            #pragma unroll
            for (int n = 0; n < 2; ++n)
                #pragma unroll
                for (int r = 0; r < 4; ++r) {
                    int row = q * 4 + r;
                    int col = wv * 32 + n * 16 + ln;
                    int off = (row * 512 + col) ^ ((row & 7) << 4);
                    float t127 = th1[n][r] * 127.f;
                    float hc = rintf(t127);
                    h1c[off] = (char)(int)hc;
                    h1f[off] = (char)(int)rintf((t127 - hc) * 127.f);
                }
            // published by next step's BAR_A
        } else {
            #pragma unroll
            for (int n = 0; n < 2; ++n)
                #pragma unroll
                for (int r = 0; r < 4; ++r)
                    finalb[(q * 4 + r) * Uu + wv * 32 + n * 16 + ln] = th1[n][r];
        }
    }

    // ---------------- epilogue ----------------
    asm volatile("s_waitcnt vmcnt(0) lgkmcnt(0)" ::: "memory");
    __builtin_amdgcn_sched_barrier(0);
    __builtin_amdgcn_s_barrier();
    __builtin_amdgcn_sched_barrier(0);

    // out[row] = sigmoid(h1[row,:] @ Wout + bout); wave wv -> row wv
    {
        float s = 0.f;
        #pragma unroll
        for (int j = 0; j < 8; ++j)
            s += finalb[wv * Uu + lane * 8 + j] * wout8[j];
        #pragma unroll
        for (int off = 32; off; off >>= 1) s += __shfl_xor(s, off);
        if (lane == 0) out[bbase + wv] = 1.f / (1.f + __expf(-(s + boutv)));
    }
}

extern "C" void kernel_launch(void* const* d_in, const int* in_sizes, int n_in,
                              void* d_out, int out_size, void* d_ws, size_t ws_size,
                              hipStream_t stream) {
    const int*   tokens = (const int*)d_in[0];
    const float* emb    = (const float*)d_in[1];
    const float* W0     = (const float*)d_in[2];
    const float* U0     = (const float*)d_in[3];
    const float* b0     = (const float*)d_in[4];
    const float* W1     = (const float*)d_in[5];
    const float* U1     = (const float*)d_in[6];
    const float* b1     = (const float*)d_in[7];
    const float* Wout   = (const float*)d_in[8];
    const float* bout   = (const float*)d_in[9];
    float* outp = (float*)d_out;

    char* ws = (char*)d_ws;
    float* embW0 = (float*)ws;                          // 20,480,000 B
    char* pW = ws + 20480000;                           // 24*32KB = 786,432 B (int8)
    float* scl = (float*)(ws + 20480000 + 786432);      // 1536 per-column absmax

    hipLaunchKernelGGL(k_embw0, dim3(Vv / 4), dim3(512), 0, stream, emb, W0, b0, embW0);
    hipLaunchKernelGGL(k_scale, dim3(384), dim3(256), 0, stream, U0, W1, U1, scl);
    hipLaunchKernelGGL(k_pack, dim3(192), dim3(256), 0, stream, U0, W1, U1, scl, pW);
    hipLaunchKernelGGL(k_rnn, dim3(NBLK), dim3(1024), 0, stream,
                       tokens, embW0, pW, scl, b1, Wout, bout, outp);
}

// Round 16
// 884.021 us; speedup vs baseline: 8.6202x; 1.0023x over previous
//
#include <hip/hip_runtime.h>
#include <hip/hip_bf16.h>
#include <math.h>

#define Tt 80
#define Vv 10000
#define Ee 100
#define Uu 512
#define ROWS 16
#define NBLK 256
#define SLICE_B 32768
#define NSLICE 24   // 8 U0 + 8x(W1,U1) interleaved, K=64 per slice (int8)

typedef __attribute__((ext_vector_type(4))) int i32x4;
typedef __attribute__((ext_vector_type(4))) unsigned u32x4;

__device__ __forceinline__ i32x4 as_i4(u32x4 v) {
    union { u32x4 u; i32x4 i; } p;
    p.u = v;
    return p.i;
}

// branch-free tanh via exp; clamp keeps e finite
__device__ __forceinline__ float tanh_fast(float x) {
    float z = fminf(fmaxf(x, -15.f), 15.f);
    float e = __expf(2.f * z);
    return (e - 1.f) / (e + 1.f);
}

// ---------------- P1: embW0 = emb@W0 + b0 (fp32, exact input term; 20MB, L3) ----------------
__global__ __launch_bounds__(512) void k_embw0(const float* __restrict__ emb,
                                               const float* __restrict__ W0,
                                               const float* __restrict__ b0,
                                               float* __restrict__ embW0) {
    __shared__ float semb[4][Ee];
    int v0 = blockIdx.x * 4;
    int tid = threadIdx.x;
    if (tid < 4 * Ee) semb[tid / Ee][tid % Ee] = emb[(v0 + tid / Ee) * Ee + tid % Ee];
    __syncthreads();
    float b = b0[tid];
    for (int vl = 0; vl < 4; ++vl) {
        float a = 0.f;
        #pragma unroll 4
        for (int e = 0; e < Ee; ++e) a += semb[vl][e] * W0[e * Uu + tid];
        embW0[(v0 + vl) * Uu + tid] = a + b;
    }
}

// ---------------- P2a: per-column absmax for U0, W1, U1 -> scl[1536] ----------------
__global__ __launch_bounds__(256) void k_scale(const float* __restrict__ U0,
                                               const float* __restrict__ W1,
                                               const float* __restrict__ U1,
                                               float* __restrict__ scl) {
    int w = blockIdx.x * 4 + (threadIdx.x >> 6);   // wave id = column slot, 0..1535
    int lane = threadIdx.x & 63;
    int mat = w >> 9, col = w & 511;
    const float* src = (mat == 0) ? U0 : (mat == 1) ? W1 : U1;
    float v = 0.f;
    #pragma unroll
    for (int i = 0; i < 8; ++i) v = fmaxf(v, fabsf(src[(lane + i * 64) * Uu + col]));
    #pragma unroll
    for (int o = 32; o; o >>= 1) v = fmaxf(v, __shfl_xor(v, o));
    if (lane == 0) scl[w] = v;
}

// ---------------- P2b: pack into 24 slice-major 32KB int8 K64-slices, per-col scale ----------------
// S<8: U0 slot S (scale scl[col]). S>=8: s2=S-8, slot=s2>>1, mat=(s2&1)?U1:W1
// (combined scale max(scl[512+col], scl[1024+col])).
__global__ __launch_bounds__(256) void k_pack(const float* __restrict__ U0,
                                              const float* __restrict__ W1,
                                              const float* __restrict__ U1,
                                              const float* __restrict__ scl,
                                              char* __restrict__ pW) {
    int gid = blockIdx.x * 256 + threadIdx.x;   // 0 .. 49151 (24 * 32 * 64)
    int S = gid >> 11;
    int ntg = (gid >> 6) & 31;
    int lane = gid & 63;
    int col = ntg * 16 + (lane & 15);
    const float* src;
    int slot;
    float a;
    if (S < 8) { src = U0; slot = S; a = scl[col]; }
    else {
        int s2 = S - 8;
        slot = s2 >> 1;
        src = (s2 & 1) ? U1 : W1;
        a = fmaxf(scl[512 + col], scl[1024 + col]);
    }
    float inv = 127.0f / a;
    int k0 = slot * 64 + (lane >> 4) * 16;
    union { char c[16]; uint4 u; } v;
    #pragma unroll
    for (int j = 0; j < 16; ++j) {
        int q = (int)rintf(src[(k0 + j) * Uu + col] * inv);
        q = q > 127 ? 127 : (q < -127 ? -127 : q);
        v.c[j] = (char)q;
    }
    *(uint4*)(pW + (size_t)gid * 16) = v.u;
}

// counted vmcnt wait + scheduler fence (rule #18)
#define VMW(N) do { asm volatile("s_waitcnt vmcnt(" #N ")" ::: "memory"); \
    __builtin_amdgcn_sched_barrier(0); } while (0)

// h-hazard barrier: drains LDS only; vmcnt queue (weight pipeline) stays in flight
#define LG_SYNC() do { asm volatile("s_waitcnt lgkmcnt(0)" ::: "memory"); \
    __builtin_amdgcn_sched_barrier(0); __builtin_amdgcn_s_barrier(); \
    __builtin_amdgcn_sched_barrier(0); } while (0)

// issue this wave's 2 B-fragments of slice S into register ring slot
#define BISSUE(S, slot) do { \
    const char* wa_ = pWb + wvoff + (size_t)(S) * SLICE_B; \
    asm volatile("global_load_dwordx4 %0, %2, off\n\t" \
                 "global_load_dwordx4 %1, %2, off offset:1024" \
                 : "=&v"(bf[slot][0]), "=&v"(bf[slot][1]) \
                 : "v"(wa_)); \
} while (0)

// issue the 8 gather dwords for step T (8 vmem instructions, counted)
#define GISSUE(T) do { \
    _Pragma("unroll") \
    for (int r_ = 0; r_ < 4; ++r_) { \
        int tk_ = stok[(q * 4 + r_) * Tt + (T)]; \
        const float* ga_ = embW0 + (size_t)tk_ * Uu + wv * 32 + ln; \
        asm volatile("global_load_dword %0, %2, off\n\t" \
                     "global_load_dword %1, %2, off offset:64" \
                     : "=&v"(gx[0][r_]), "=&v"(gx[1][r_]) \
                     : "v"(ga_)); \
    } \
} while (0)

__global__ __launch_bounds__(1024, 4)
void k_rnn(const int* __restrict__ tokens,
           const float* __restrict__ embW0,
           const char* __restrict__ pWu,
           const float* __restrict__ scl,
           const float* __restrict__ b1,
           const float* __restrict__ Wout,
           const float* __restrict__ bout,
           float* __restrict__ out) {
    __shared__ __align__(16) char smem[136192];
    char* h0c = smem;                    // int8 coarse [16][512] swizzled, 8KB
    char* h0f = smem + 8192;             // int8 fine
    char* h1c = smem + 16384;
    char* h1f = smem + 24576;
    int* stok = (int*)(smem + 32768);    // [16][80] tokens, 5120B
    char* ldsW = smem + 37888;           // persistent slices 0,1,2 (96KB)
    float* finalb = (float*)smem;        // fp32 [16][512] overlay for epilogue (32KB)

    const int tid = threadIdx.x;
    const int lane = tid & 63;
    const int wv = tid >> 6;             // 0..15, owns cols wv*32 .. wv*32+31
    const int q = lane >> 4;
    const int ln = lane & 15;
    const int bbase = blockIdx.x * ROWS;
    const int swz = (ln & 7) << 4;
    const char* pWb = pWu;
    const int wvoff = wv * 2048 + lane * 16;   // byte offset of ntg=wv*2, this lane
    const float r127 = 1.0f / 127.0f;

    // zero h buffers (32KB)
    {
        uint4 z = {0u, 0u, 0u, 0u};
        #pragma unroll
        for (int i = 0; i < 2; ++i) ((uint4*)smem)[tid + i * 1024] = z;
    }
    // stage token slab
    for (int i = tid; i < ROWS * Tt; i += 1024) stok[i] = tokens[bbase * Tt + i];
    __syncthreads();   // stok + h zeros visible before any thread reads them

    // stage persistent slices 0..2 into LDS via plain load + ds_write (96KB, once).
    // Linear copy preserves the slice-major layout; compiler manages all waits.
    #pragma unroll
    for (int k = 0; k < 6; ++k) {
        uint4 v = *(const uint4*)(pWb + ((size_t)(k * 1024 + tid)) * 16);
        *(uint4*)(ldsW + (k * 1024 + tid) * 16) = v;
    }

    // per-column dequant constants: DQ = col_absmax / 127^2
    float DQ0[2], DQ1[2], b1c[2];
    #pragma unroll
    for (int n = 0; n < 2; ++n) {
        int col = wv * 32 + n * 16 + ln;
        DQ0[n] = scl[col] / 16129.0f;
        DQ1[n] = fmaxf(scl[512 + col], scl[1024 + col]) / 16129.0f;
        b1c[n] = b1[col];
    }

    u32x4 bf[3][2];    // 3-slot register ring for streamed slices
    float gx[2][4];    // input-term gather (fp32, incl. b0)

    GISSUE(0);         // safe: stok published by the barrier above
    asm volatile("s_waitcnt vmcnt(0)" ::: "memory");
    __builtin_amdgcn_sched_barrier(0);
    __syncthreads();   // ldsW staged & visible; asm-FIFO empty here

    // prime the stream: slices 3,4 in flight (lookahead 2)
    BISSUE(3, 0);
    BISSUE(4, 1);

    for (int t = 0; t < Tt; ++t) {
        // ---------- layer 0: phases p=0..7 (U0); p<3 from LDS, p>=3 streamed ----------
        i32x4 accC[2], accF[2];
        #pragma unroll
        for (int n = 0; n < 2; ++n)
            #pragma unroll
            for (int r = 0; r < 4; ++r) { accC[n][r] = 0; accF[n][r] = 0; }

        #pragma unroll
        for (int p = 0; p < 8; ++p) {
            i32x4 bb0, bb1;
            if (p < 3) {
                const char* ls = ldsW + p * SLICE_B + wvoff;
                bb0 = *(const i32x4*)ls;
                bb1 = *(const i32x4*)(ls + 1024);
            } else {
                VMW(2);                          // slice p landed (issued 2 phases ago)
                BISSUE(p + 2, (p - 1) % 3);      // lookahead 2
                bb0 = as_i4(bf[p % 3][0]);
                bb1 = as_i4(bf[p % 3][1]);
            }
            int off = (ln * 512 + p * 64 + q * 16) ^ swz;
            i32x4 aC = *(const i32x4*)(h0c + off);
            i32x4 aF = *(const i32x4*)(h0f + off);
            accC[0] = __builtin_amdgcn_mfma_i32_16x16x64_i8(aC, bb0, accC[0], 0, 0, 0);
            accC[1] = __builtin_amdgcn_mfma_i32_16x16x64_i8(aC, bb1, accC[1], 0, 0, 0);
            accF[0] = __builtin_amdgcn_mfma_i32_16x16x64_i8(aF, bb0, accF[0], 0, 0, 0);
            accF[1] = __builtin_amdgcn_mfma_i32_16x16x64_i8(aF, bb1, accF[1], 0, 0, 0);
        }

        // dequant (per-col scale) + exact fp32 input term + tanh
        float th0[2][4];
        #pragma unroll
        for (int n = 0; n < 2; ++n)
            #pragma unroll
            for (int r = 0; r < 4; ++r)
                th0[n][r] = tanh_fast(gx[n][r] + DQ0[n] * ((float)accC[n][r] + (float)accF[n][r] * r127));

        LG_SYNC();   // BAR_A: all waves done reading h0_old (h1 writes of t-1 drained)
        #pragma unroll
        for (int n = 0; n < 2; ++n)
            #pragma unroll
            for (int r = 0; r < 4; ++r) {
                int row = q * 4 + r;
                int col = wv * 32 + n * 16 + ln;
                int off = (row * 512 + col) ^ ((row & 7) << 4);
                float t127 = th0[n][r] * 127.f;
                float hc = rintf(t127);
                h0c[off] = (char)(int)hc;
                h0f[off] = (char)(int)rintf((t127 - hc) * 127.f);
            }
        LG_SYNC();   // BAR_B: h0_new published

        // issue next step's gathers (uniform count; t=79 data unused)
        GISSUE(t + 1 < Tt ? t + 1 : 0);

        // ---------- layer 1: phases p=8..23 (W1/U1 interleaved, combined scale) ----------
        i32x4 a1C[2], a1F[2];
        #pragma unroll
        for (int n = 0; n < 2; ++n)
            #pragma unroll
            for (int r = 0; r < 4; ++r) { a1C[n][r] = 0; a1F[n][r] = 0; }

        #pragma unroll
        for (int p = 8; p < 24; ++p) {
            // FIFO before wait: p=8: [S8(2),S9(2),G(8)]=12 -> VMW(10);
            // p=9: [S9(2),G(8),S10(2)]=12 -> VMW(10); p=10: [G(8),S10,S11]=12 -> VMW(4);
            // p>=11: [Sp,Sp+1]=4 -> VMW(2).
            if      (p == 8 || p == 9) { VMW(10); }
            else if (p == 10)          { VMW(4);  }
            else                       { VMW(2);  }
            if      (p <= 21) BISSUE(p + 2, (p - 1) % 3);
            else if (p == 22) BISSUE(3, 0);   // wrap: next step's S3, slot (22-1)%3=0
            else              BISSUE(4, 1);   // wrap: next step's S4, slot (23-1)%3=1
            const int idx = p - 8;
            const int k2 = idx >> 1;
            const char* hc_ = (idx & 1) ? h1c : h0c;   // even: W1 x h0_new, odd: U1 x h1_old
            const char* hf_ = (idx & 1) ? h1f : h0f;
            int off = (ln * 512 + k2 * 64 + q * 16) ^ swz;
            i32x4 aC = *(const i32x4*)(hc_ + off);
            i32x4 aF = *(const i32x4*)(hf_ + off);
            i32x4 bb0 = as_i4(bf[p % 3][0]);
            i32x4 bb1 = as_i4(bf[p % 3][1]);
            a1C[0] = __builtin_amdgcn_mfma_i32_16x16x64_i8(aC, bb0, a1C[0], 0, 0, 0);
            a1C[1] = __builtin_amdgcn_mfma_i32_16x16x64_i8(aC, bb1, a1C[1], 0, 0, 0);
            a1F[0] = __builtin_amdgcn_mfma_i32_16x16x64_i8(aF, bb0, a1F[0], 0, 0, 0);
            a1F[1] = __builtin_amdgcn_mfma_i32_16x16x64_i8(aF, bb1, a1F[1], 0, 0, 0);
        }

        float th1[2][4];
        #pragma unroll
        for (int n = 0; n < 2; ++n)
            #pragma unroll
            for (int r = 0; r < 4; ++r)
                th1[n][r] = tanh_fast(b1c[n] + DQ1[n] * ((float)a1C[n][r] + (float)a1F[n][r] * r127));

        LG_SYNC();   // BAR_C: all waves done reading h1_old (and h0_new)
        if (t < Tt - 1) {
            #pragma unroll
            for (int n = 0; n < 2; ++n)
                #pragma unroll
                for (int r = 0; r < 4; ++r) {
                    int row = q * 4 + r;
                    int col = wv * 32 + n * 16 + ln;
                    int off = (row * 512 + col) ^ ((row & 7) << 4);
                    float t127 = th1[n][r] * 127.f;
                    float hc = rintf(t127);
                    h1c[off] = (char)(int)hc;
                    h1f[off] = (char)(int)rintf((t127 - hc) * 127.f);
                }
            // published by next step's BAR_A
        } else {
            #pragma unroll
            for (int n = 0; n < 2; ++n)
                #pragma unroll
                for (int r = 0; r < 4; ++r)
                    finalb[(q * 4 + r) * Uu + wv * 32 + n * 16 + ln] = th1[n][r];
        }
    }

    // ---------------- epilogue ----------------
    asm volatile("s_waitcnt vmcnt(0) lgkmcnt(0)" ::: "memory");
    __builtin_amdgcn_sched_barrier(0);
    __builtin_amdgcn_s_barrier();
    __builtin_amdgcn_sched_barrier(0);

    // out[row] = sigmoid(h1[row,:] @ Wout + bout); wave wv -> row wv
    {
        float s = 0.f;
        #pragma unroll
        for (int j = 0; j < 8; ++j)
            s += finalb[wv * Uu + lane * 8 + j] * Wout[lane * 8 + j];
        #pragma unroll
        for (int off = 32; off; off >>= 1) s += __shfl_xor(s, off);
        if (lane == 0) out[bbase + wv] = 1.f / (1.f + __expf(-(s + bout[0])));
    }
}

extern "C" void kernel_launch(void* const* d_in, const int* in_sizes, int n_in,
                              void* d_out, int out_size, void* d_ws, size_t ws_size,
                              hipStream_t stream) {
    const int*   tokens = (const int*)d_in[0];
    const float* emb    = (const float*)d_in[1];
    const float* W0     = (const float*)d_in[2];
    const float* U0     = (const float*)d_in[3];
    const float* b0     = (const float*)d_in[4];
    const float* W1     = (const float*)d_in[5];
    const float* U1     = (const float*)d_in[6];
    const float* b1     = (const float*)d_in[7];
    const float* Wout   = (const float*)d_in[8];
    const float* bout   = (const float*)d_in[9];
    float* outp = (float*)d_out;

    char* ws = (char*)d_ws;
    float* embW0 = (float*)ws;                          // 20,480,000 B
    char* pW = ws + 20480000;                           // 24*32KB = 786,432 B (int8)
    float* scl = (float*)(ws + 20480000 + 786432);      // 1536 per-column absmax

    hipLaunchKernelGGL(k_embw0, dim3(Vv / 4), dim3(512), 0, stream, emb, W0, b0, embW0);
    hipLaunchKernelGGL(k_scale, dim3(384), dim3(256), 0, stream, U0, W1, U1, scl);
    hipLaunchKernelGGL(k_pack, dim3(192), dim3(256), 0, stream, U0, W1, U1, scl, pW);
    hipLaunchKernelGGL(k_rnn, dim3(NBLK), dim3(1024), 0, stream,
                       tokens, embW0, pW, scl, b1, Wout, bout, outp);
}